// Round 1
// 533.661 us; speedup vs baseline: 1.1406x; 1.1406x over previous
//
#include <hip/hip_runtime.h>
#include <cstdint>
#include <cstddef>

// ---- types ----
typedef _Float16 h8_t  __attribute__((ext_vector_type(8)));
typedef _Float16 h4_t  __attribute__((ext_vector_type(4)));
typedef float    f32x4 __attribute__((ext_vector_type(4)));

#define B_DIM   8192
#define IN_DIM  4096
#define OUT_DIM 4096
#define BN_EPS  1e-5f
#define SLOPE   0.01f
#define NT      (IN_DIM / 64)   // 64 K-tiles of BK=64

// address-space casts for global_load_lds
#define AS_G(p) ((__attribute__((address_space(1))) void*)(p))
#define AS_L(p) ((__attribute__((address_space(3))) void*)(p))

// ---------------------------------------------------------------------------
// Kernel 1 (fused): Xh = fp16(x)  AND  per-column partial sum/sumsq.
// (unchanged from previous round — verified)
// ---------------------------------------------------------------------------
__global__ __launch_bounds__(256) void k_fused_x(const float* __restrict__ x,
                                                 _Float16* __restrict__ Xh,
                                                 float* __restrict__ partial)
{
    const int col8 = blockIdx.x * 256 + threadIdx.x;   // float8 index in row
    const int r0   = blockIdx.y * 32;
    const f32x4* xr = (const f32x4*)x + (size_t)r0 * (IN_DIM / 4) + col8 * 2;
    h8_t* xo = (h8_t*)Xh + (size_t)r0 * (IN_DIM / 8) + col8;

    f32x4 sa  = {0.f, 0.f, 0.f, 0.f}, sb  = {0.f, 0.f, 0.f, 0.f};
    f32x4 qa  = {0.f, 0.f, 0.f, 0.f}, qb  = {0.f, 0.f, 0.f, 0.f};
#pragma unroll 4
    for (int r = 0; r < 32; ++r) {
        const f32x4 a = xr[(size_t)r * (IN_DIM / 4) + 0];
        const f32x4 b = xr[(size_t)r * (IN_DIM / 4) + 1];
        sa += a;  qa += a * a;
        sb += b;  qb += b * b;
        h8_t h;
        h[0] = (_Float16)a[0]; h[1] = (_Float16)a[1];
        h[2] = (_Float16)a[2]; h[3] = (_Float16)a[3];
        h[4] = (_Float16)b[0]; h[5] = (_Float16)b[1];
        h[6] = (_Float16)b[2]; h[7] = (_Float16)b[3];
        xo[(size_t)r * (IN_DIM / 8)] = h;
    }
    f32x4* ps = (f32x4*)partial;
    const size_t rowS = (size_t)(blockIdx.y * 2 + 0) * (IN_DIM / 4);
    const size_t rowQ = (size_t)(blockIdx.y * 2 + 1) * (IN_DIM / 4);
    ps[rowS + col8 * 2 + 0] = sa;
    ps[rowS + col8 * 2 + 1] = sb;
    ps[rowQ + col8 * 2 + 0] = qa;
    ps[rowQ + col8 * 2 + 1] = qb;
}

// ---------------------------------------------------------------------------
// Kernel 2: reduce 256 partial chunk-pairs -> scale/shift per column.
// (unchanged)
// ---------------------------------------------------------------------------
__global__ __launch_bounds__(256) void k_stats_final(const float* __restrict__ partial,
                                                     const float* __restrict__ gamma,
                                                     const float* __restrict__ beta,
                                                     float* __restrict__ scale,
                                                     float* __restrict__ shiftv)
{
    __shared__ float rs[4][64];
    __shared__ float rq[4][64];
    const int g   = threadIdx.x >> 6;          // chunk group 0..3
    const int l   = threadIdx.x & 63;
    const int col = blockIdx.x * 64 + l;
    float s = 0.f, sq = 0.f;
#pragma unroll 8
    for (int c = 0; c < 64; ++c) {
        const int ch = g * 64 + c;
        s  += partial[(size_t)(ch * 2 + 0) * IN_DIM + col];
        sq += partial[(size_t)(ch * 2 + 1) * IN_DIM + col];
    }
    rs[g][l] = s;
    rq[g][l] = sq;
    __syncthreads();
    if (g == 0) {
        s  = rs[0][l] + rs[1][l] + rs[2][l] + rs[3][l];
        sq = rq[0][l] + rq[1][l] + rq[2][l] + rq[3][l];
        const float inv  = 1.0f / (float)B_DIM;
        const float mean = s * inv;
        const float var  = sq * inv - mean * mean;   // biased
        const float sc   = gamma[col] * rsqrtf(var + BN_EPS);
        scale[col]  = sc;
        shiftv[col] = beta[col] - mean * sc;
    }
}

// ---------------------------------------------------------------------------
// Kernel 3: per W-row o:  Wh[o,i] = fp16(W[o,i]*s[i]);  bp[o] = b[o] + sum_i t[i]*W[o,i]
// (unchanged)
// ---------------------------------------------------------------------------
__global__ __launch_bounds__(256) void k_prep_w(const float* __restrict__ W,
                                                const float* __restrict__ scale,
                                                const float* __restrict__ shiftv,
                                                const float* __restrict__ b,
                                                _Float16* __restrict__ Wh,
                                                float* __restrict__ bp)
{
    const int wave = threadIdx.x >> 6;
    const int lane = threadIdx.x & 63;
    const int row  = blockIdx.x * 4 + wave;
    const f32x4* wr = (const f32x4*)(W + (size_t)row * IN_DIM);
    const f32x4* sv = (const f32x4*)scale;
    const f32x4* tv = (const f32x4*)shiftv;
    h4_t* out = (h4_t*)(Wh + (size_t)row * IN_DIM);
    float dot = 0.f;
#pragma unroll
    for (int it = 0; it < IN_DIM / 4 / 64; ++it) {   // 16 iters
        const int c = it * 64 + lane;
        const f32x4 w = wr[c];
        const f32x4 s = sv[c];
        const f32x4 t = tv[c];
        dot += w[0] * t[0] + w[1] * t[1] + w[2] * t[2] + w[3] * t[3];
        h4_t h;
        h[0] = (_Float16)(w[0] * s[0]);
        h[1] = (_Float16)(w[1] * s[1]);
        h[2] = (_Float16)(w[2] * s[2]);
        h[3] = (_Float16)(w[3] * s[3]);
        out[c] = h;
    }
#pragma unroll
    for (int off = 32; off >= 1; off >>= 1)
        dot += __shfl_down(dot, off, 64);
    if (lane == 0) bp[row] = b[row] + dot;
}

// ---------------------------------------------------------------------------
// Kernel 4: GEMM  out[m][n] = leaky(sum_k Xh[m][k]*Wh[n][k] + bp[n])
//
// 256x256 tile, BK=64, 8 waves (2Mx4N), 128 KiB double-buffered LDS,
// 4-phase schedule per K-tile with counted vmcnt(6) (loads live across
// barriers), XOR k-chunk swizzle (slot = kchunk ^ (row&7)) applied to the
// global SOURCE of global_load_lds and the same XOR on ds_read -> all
// ds_read_b128 are perfectly bank-balanced (8 touches/bank).
//
// Half-tile issue order per tile t: B0,B1,A0 issued during tile t-2's
// phases 2,3,4; A1 during tile t-1's phase 1. Per-wave read schedule:
// all B frags + A[0..1] @P1, A[2..3] @P2, A[4..7] @P3, none @P4 -> every
// region's global last-read strictly precedes its overwrite issue phase.
// vmcnt(6) at end of phase 4 leaves exactly the next tile's 3 newest
// half-tiles in flight and guarantees tile t+1 fully resident.
// ---------------------------------------------------------------------------
#define STAGE_A(tt, hf) do {                                                          \
    _Float16* _d = ldsA + ((tt) & 1) * 16384 + (hf) * 8192;                           \
    const _Float16* _s = aSrc + (size_t)(hf) * 128 * IN_DIM                           \
                              + (size_t)(((tt) & (NT - 1)) * 64);                     \
    __builtin_amdgcn_global_load_lds(AS_G(_s), AS_L(_d), 16, 0, 0);                   \
    __builtin_amdgcn_global_load_lds(AS_G(_s + (size_t)64 * IN_DIM),                  \
                                     AS_L(_d + 4096), 16, 0, 0);                      \
} while (0)

#define STAGE_B(tt, hf) do {                                                          \
    _Float16* _d = ldsB + ((tt) & 1) * 16384 + (hf) * 8192;                           \
    const _Float16* _s = bSrc + (size_t)(hf) * 128 * IN_DIM                           \
                              + (size_t)(((tt) & (NT - 1)) * 64);                     \
    __builtin_amdgcn_global_load_lds(AS_G(_s), AS_L(_d), 16, 0, 0);                   \
    __builtin_amdgcn_global_load_lds(AS_G(_s + (size_t)64 * IN_DIM),                  \
                                     AS_L(_d + 4096), 16, 0, 0);                      \
} while (0)

#define LDA2(dst, ib)                                                                 \
    _Pragma("unroll")                                                                 \
    for (int i = 0; i < 2; ++i) {                                                     \
        dst[i][0] = *(const h8_t*)(Ab + ((ib) + i) * 1024 + sOff0);                   \
        dst[i][1] = *(const h8_t*)(Ab + ((ib) + i) * 1024 + sOff1);                   \
    }

#define MFMA_PAIR(ib, aFr)                                                            \
    __builtin_amdgcn_s_setprio(1);                                                    \
    _Pragma("unroll")                                                                 \
    for (int i = 0; i < 2; ++i)                                                       \
    _Pragma("unroll")                                                                 \
    for (int j = 0; j < 4; ++j) {                                                     \
        acc[(ib) + i][j] = __builtin_amdgcn_mfma_f32_16x16x32_f16(                    \
            aFr[i][0], bF[j][0], acc[(ib) + i][j], 0, 0, 0);                          \
        acc[(ib) + i][j] = __builtin_amdgcn_mfma_f32_16x16x32_f16(                    \
            aFr[i][1], bF[j][1], acc[(ib) + i][j], 0, 0, 0);                          \
    }                                                                                 \
    __builtin_amdgcn_s_setprio(0);

__global__ __launch_bounds__(512, 2) void k_gemm(const _Float16* __restrict__ H,
                                                 const _Float16* __restrict__ Wh,
                                                 const float* __restrict__ bias,
                                                 float* __restrict__ out)
{
    __shared__ _Float16 Ah[2 * 256 * 64];   // 64 KiB
    __shared__ _Float16 Bh[2 * 256 * 64];   // 64 KiB

    const int tid  = threadIdx.x;
    const int wave = tid >> 6;
    const int lane = tid & 63;
    const int quad = lane >> 4;     // 0..3
    const int l16  = lane & 15;     // 0..15
    const int wm   = wave >> 2;     // 0..1  (M wave row)
    const int wn   = wave & 3;      // 0..3  (N wave col)

    const int rowBase = blockIdx.y * 256;
    const int colBase = blockIdx.x * 256;

    // ---- staging addressing (linear LDS dest; swizzle folded into global src)
    const int ldRow = tid >> 3;                     // 0..63 rows per it-round
    const int kl    = (tid & 7) ^ (ldRow & 7);      // inverse-swizzled k-chunk
    const _Float16* aSrc = H  + (size_t)(rowBase + ldRow) * IN_DIM + kl * 8;
    const _Float16* bSrc = Wh + (size_t)(colBase + ldRow) * IN_DIM + kl * 8;
    _Float16* ldsA = Ah + wave * 512;               // wave-uniform LDS base
    _Float16* ldsB = Bh + wave * 512;

    // ---- fragment read addressing (same XOR on the read side)
    const int sA      = quad ^ (l16 & 7);
    const int sOff0   = sA * 8;                     // ks=0 slot
    const int sOff1   = (sA ^ 4) * 8;               // ks=1 slot
    const int aRowOff = (wm * 128 + l16) * 64;
    const int bRowOff = (wn * 64  + l16) * 64;

    f32x4 acc[8][4];
#pragma unroll
    for (int i = 0; i < 8; ++i)
#pragma unroll
        for (int j = 0; j < 4; ++j) {
            f32x4 z = {0.f, 0.f, 0.f, 0.f};
            acc[i][j] = z;
        }

    // ---- prologue: tile0 {B0,B1,A0,A1}, tile1 {B0,B1,A0} = 14 loads
    STAGE_B(0, 0); STAGE_B(0, 1); STAGE_A(0, 0); STAGE_A(0, 1);
    STAGE_B(1, 0); STAGE_B(1, 1); STAGE_A(1, 0);
    asm volatile("s_waitcnt vmcnt(6)" ::: "memory");   // tile0 fully resident
    __builtin_amdgcn_s_barrier();

    // ---- main loop: one K-tile per iteration, 4 phases
#pragma unroll 2
    for (int t = 0; t < NT; ++t) {
        const int buf = t & 1;
        const _Float16* Ab = Ah + buf * 16384 + aRowOff;
        const _Float16* Bb = Bh + buf * 16384 + bRowOff;
        h8_t bF[4][2], aA[2][2], aB[2][2], aC[2][2], aD[2][2];

        // ---- phase 1: read B(all) + A[0..1]; issue next tile's A1
#pragma unroll
        for (int j = 0; j < 4; ++j) {
            bF[j][0] = *(const h8_t*)(Bb + j * 1024 + sOff0);
            bF[j][1] = *(const h8_t*)(Bb + j * 1024 + sOff1);
        }
        LDA2(aA, 0);
        STAGE_A(t + 1, 1);
        __builtin_amdgcn_s_barrier();
        asm volatile("s_waitcnt lgkmcnt(0)" ::: "memory");
        MFMA_PAIR(0, aA);
        asm volatile("" ::: "memory");
        __builtin_amdgcn_s_barrier();

        // ---- phase 2: read A[2..3]; issue tile t+2's B0 (B0 last read @P1)
        LDA2(aB, 2);
        STAGE_B(t + 2, 0);
        __builtin_amdgcn_s_barrier();
        asm volatile("s_waitcnt lgkmcnt(0)" ::: "memory");
        MFMA_PAIR(2, aB);
        asm volatile("" ::: "memory");
        __builtin_amdgcn_s_barrier();

        // ---- phase 3: read A[4..7]; issue tile t+2's B1 (B1 last read @P1)
        LDA2(aC, 4);
        LDA2(aD, 6);
        STAGE_B(t + 2, 1);
        __builtin_amdgcn_s_barrier();
        asm volatile("s_waitcnt lgkmcnt(0)" ::: "memory");
        MFMA_PAIR(4, aC);
        asm volatile("" ::: "memory");
        __builtin_amdgcn_s_barrier();

        // ---- phase 4: no reads; issue tile t+2's A0 (A0 last read @P3);
        //      counted vmcnt -> next tile resident, 3 half-tiles stay in flight
        STAGE_A(t + 2, 0);
        __builtin_amdgcn_s_barrier();
        MFMA_PAIR(6, aD);
        asm volatile("s_waitcnt vmcnt(6)" ::: "memory");
        __builtin_amdgcn_s_barrier();
    }

    // ---- epilogue: bias + LeakyReLU. C/D: col = lane&15, row = quad*4 + reg.
#pragma unroll
    for (int j = 0; j < 4; ++j) {
        const int col = colBase + wn * 64 + j * 16 + l16;
        const float bj = bias[col];
#pragma unroll
        for (int i = 0; i < 8; ++i) {
            const int row0 = rowBase + wm * 128 + i * 16 + quad * 4;
#pragma unroll
            for (int r = 0; r < 4; ++r) {
                float v = acc[i][j][r] + bj;
                v = (v >= 0.f) ? v : SLOPE * v;
                out[(size_t)(row0 + r) * OUT_DIM + col] = v;
            }
        }
    }
}

// ---------------------------------------------------------------------------
extern "C" void kernel_launch(void* const* d_in, const int* in_sizes, int n_in,
                              void* d_out, int out_size, void* d_ws, size_t ws_size,
                              hipStream_t stream)
{
    const float* x     = (const float*)d_in[0];   // [8192,4096]
    const float* gamma = (const float*)d_in[1];   // [4096]
    const float* beta  = (const float*)d_in[2];   // [4096]
    const float* W     = (const float*)d_in[3];   // [4096,4096] row-major [OUT][IN]
    const float* bias  = (const float*)d_in[4];   // [4096]
    float* out = (float*)d_out;                   // [8192,4096]

    // workspace layout (16B-aligned):
    //   Xh  : B*IN fp16        = 64 MB
    //   Wh  : OUT*IN fp16      = 32 MB
    //   part: 512*IN fp32      = 8 MB   (256 chunk-pairs)
    //   scale, shiftv : IN fp32 ; bp : OUT fp32
    char* ws = (char*)d_ws;
    _Float16* Xh = (_Float16*)ws;
    _Float16* Wh = (_Float16*)(ws + (size_t)B_DIM * IN_DIM * sizeof(_Float16));
    float* partial = (float*)(ws + (size_t)B_DIM * IN_DIM * sizeof(_Float16)
                                 + (size_t)OUT_DIM * IN_DIM * sizeof(_Float16));
    float* scale  = partial + (size_t)512 * IN_DIM;
    float* shiftv = scale + IN_DIM;
    float* bp     = shiftv + IN_DIM;

    k_fused_x    <<<dim3(IN_DIM / 2048, B_DIM / 32), 256, 0, stream>>>(x, Xh, partial);
    k_stats_final<<<dim3(IN_DIM / 64), 256, 0, stream>>>(partial, gamma, beta, scale, shiftv);
    k_prep_w     <<<dim3(OUT_DIM / 4), 256, 0, stream>>>(W, scale, shiftv, bias, Wh, bp);
    k_gemm       <<<dim3(OUT_DIM / 256, B_DIM / 256), 512, 0, stream>>>(Xh, Wh, bp, out);
}